// Round 15
// baseline (6138.628 us; speedup 1.0000x reference)
//
#include <hip/hip_runtime.h>
#include <hip/hip_fp16.h>
#include <stdint.h>

#define T_SEQ 1024
#define NB    64
#define VOCAB 34
#define NSPK  128
#define DTXT  512
#define HID   256
#define NMEL  80
#define GROWS 1024   // 4*HID gate rows
#define DROWS 768    // decoder rows actually used: i,g,o

typedef _Float16 f16;
typedef _Float16 f16x2 __attribute__((ext_vector_type(2)));
typedef _Float16 v8h __attribute__((ext_vector_type(8)));
typedef float v4f __attribute__((ext_vector_type(4)));

__device__ __forceinline__ float fdot2f(uint32_t a, uint32_t b, float c) {
  return __builtin_amdgcn_fdot2(__builtin_bit_cast(f16x2, a),
                                __builtin_bit_cast(f16x2, b), c, false);
}
__device__ __forceinline__ float sigm(float x) { return 1.0f / (1.0f + __expf(-x)); }
__device__ __forceinline__ float tanhf_fast(float x) {
  float e = __expf(2.0f * x);
  return 1.0f - 2.0f / (e + 1.0f);
}
// Barrier that drains LDS ops but lets global loads/stores stay in flight.
__device__ __forceinline__ void bar_vperm() {
  asm volatile("s_waitcnt lgkmcnt(0)\n\ts_barrier" ::: "memory");
  __builtin_amdgcn_sched_barrier(0);
}

// ---------------- prep kernels ----------------

__global__ void k_tp(const float* __restrict__ Wf, const float* __restrict__ Wb,
                     const float* __restrict__ emb_text, float* __restrict__ TP) {
  int blk = blockIdx.x; int dir = blk / VOCAB; int v = blk - dir * VOCAB;
  const float* W = dir ? Wb : Wf;
  const float4* e4 = (const float4*)(emb_text + (size_t)v * DTXT);
  for (int r = threadIdx.x; r < GROWS; r += 256) {
    const float4* w4 = (const float4*)(W + (size_t)r * 576);
    float a0 = 0, a1 = 0, a2 = 0, a3 = 0;
    #pragma unroll 4
    for (int d = 0; d < DTXT / 4; ++d) {
      float4 ev = e4[d], wv = w4[d];
      a0 += ev.x * wv.x; a1 += ev.y * wv.y;
      a2 += ev.z * wv.z; a3 += ev.w * wv.w;
    }
    TP[(size_t)(dir * VOCAB + v) * GROWS + r] = (a0 + a1) + (a2 + a3);
  }
}

__global__ void k_sp(const float* __restrict__ Wf, const float* __restrict__ Wb,
                     const float* __restrict__ bihf, const float* __restrict__ bhhf,
                     const float* __restrict__ bihb, const float* __restrict__ bhhb,
                     const float* __restrict__ emb_spk, float* __restrict__ SP) {
  int blk = blockIdx.x; int dir = blk >> 7; int s = blk & 127;
  const float* W  = dir ? Wb : Wf;
  const float* bi = dir ? bihb : bihf;
  const float* bh = dir ? bhhb : bhhf;
  const float4* e4 = (const float4*)(emb_spk + (size_t)s * 64);
  for (int r = threadIdx.x; r < GROWS; r += 256) {
    const float4* w4 = (const float4*)(W + (size_t)r * 576 + 512);
    float a0 = 0, a1 = 0, a2 = 0, a3 = 0;
    #pragma unroll
    for (int d = 0; d < 16; ++d) {
      float4 ev = e4[d], wv = w4[d];
      a0 += ev.x * wv.x; a1 += ev.y * wv.y;
      a2 += ev.z * wv.z; a3 += ev.w * wv.w;
    }
    SP[(size_t)(dir * NSPK + s) * GROWS + r] = bi[r] + bh[r] + (a0 + a1) + (a2 + a3);
  }
}

__global__ void k_whh(const float* __restrict__ Whhf, const float* __restrict__ Whhb,
                      f16* __restrict__ WhhH) {
  int idx = blockIdx.x * 256 + threadIdx.x;
  if (idx < 2 * GROWS * HID) {
    int dir = idx >> 18; int rem = idx & (GROWS * HID - 1);
    WhhH[idx] = (f16)(dir ? Whhb[rem] : Whhf[rem]);
  }
}

// decoder weights, row-reordered to [i(256), g(256), o(256)] (f gate unused)
__global__ void k_decw(const float* __restrict__ Wih_d, const float* __restrict__ bih_d,
                       const float* __restrict__ bhh_d,
                       f16* __restrict__ WmH, f16* __restrict__ WdH, float* __restrict__ dbias) {
  int r = blockIdx.x;                 // 0..767 in [i,g,o] space
  int src = (r < 256) ? r : (r + 256);
  const float* w = Wih_d + (size_t)src * 592;
  for (int k = threadIdx.x; k < 592; k += 256) {
    float v = w[k];
    if (k < 80) WmH[(size_t)r * 80 + k] = (f16)v;
    else        WdH[(size_t)r * 512 + (k - 80)] = (f16)v;
  }
  if (threadIdx.x == 0) dbias[r] = bih_d[src] + bhh_d[src];
}

__global__ void k_misc(const float* __restrict__ Wfc, f16* __restrict__ WfcH,
                       unsigned int* __restrict__ flags) {
  int idx = blockIdx.x * 256 + threadIdx.x;
  if (idx < NMEL * HID) WfcH[idx] = (f16)Wfc[idx];
  if (blockIdx.x == 0) flags[threadIdx.x * 64] = 0u;   // 256 padded flags
}

// ---------------- encoder: 256 WGs = (pair = dir*64+b, half); each WG owns 128
// units x 4 gates (= 512 rows, 1 row/thread, ALL 32 weight chunks in VGPRs).
// Per step the halves exchange 128 f16 of h through L3: 16 parallel uint4
// stores + one 256B-padded flag (release/acquire, agent scope, monotonic
// values, double-buffered data slots -> race-free). 84KB LDS pad forces
// 1 WG/CU so all 256 WGs are co-resident (no spin deadlock).
__launch_bounds__(512, 2)
__global__ void k_enc(const int* __restrict__ text_seq, const int* __restrict__ speaker_id,
                      const float* __restrict__ TP, const float* __restrict__ SP,
                      const uint32_t* __restrict__ WhhH_dw,
                      f16* __restrict__ Hh, uint32_t* __restrict__ Hx,
                      unsigned int* __restrict__ flags) {
  __shared__ __align__(16) uint32_t hfull[2][128];   // full h(t) f16[256], dbl-buffered
  __shared__ float pp[512];                          // gate preacts
  __shared__ int tseq[T_SEQ];
  __shared__ __align__(16) uint4 lds_pad[4800];      // 76.8KB residency pad

  int wgid = blockIdx.x;
  int pair = wgid & 127, half = wgid >> 7;
  int dir = pair >> 6, b = pair & 63;
  int tid = threadIdx.x;
  int g = tid >> 7, uu = tid & 127;
  int row = g * 256 + half * 128 + uu;

  uint4 w[32];
  {
    const uint4* wp = (const uint4*)(WhhH_dw + ((size_t)(dir << 10) + row) * 128);
    #pragma unroll
    for (int i = 0; i < 32; ++i) w[i] = wp[i];
  }
  for (int i = tid; i < T_SEQ; i += 512) tseq[i] = text_seq[b * T_SEQ + i];
  if (tid < 128) hfull[0][tid] = 0u;
  ((volatile uint32_t*)lds_pad)[tid] = 0u;           // keep pad allocated
  float sp = SP[(size_t)(dir * NSPK + speaker_id[b]) * GROWS + row];
  const float* TPd = TP + (size_t)dir * VOCAB * GROWS;
  float c_state = 0.0f;
  const unsigned myF = (unsigned)(pair * 2 + half);
  const unsigned paF = (unsigned)(pair * 2 + (half ^ 1));
  __syncthreads();

  float xcur = TPd[(size_t)tseq[dir ? (T_SEQ - 1) : 0] * GROWS + row];

  for (int n = 0; n < T_SEQ; ++n) {
    int t = dir ? (T_SEQ - 1 - n) : n;
    int tn = dir ? (T_SEQ - 2 - n) : (n + 1);
    tn = tn < 0 ? 0 : (tn > T_SEQ - 1 ? T_SEQ - 1 : tn);
    float xnext = TPd[(size_t)tseq[tn] * GROWS + row];

    float a0 = 0, a1 = 0, a2 = 0, a3 = 0;
    const uint4* h4 = (const uint4*)hfull[n & 1];
    #pragma unroll
    for (int c = 0; c < 32; ++c) {
      uint4 hv = h4[c];
      a0 = fdot2f(w[c].x, hv.x, a0);
      a1 = fdot2f(w[c].y, hv.y, a1);
      a2 = fdot2f(w[c].z, hv.z, a2);
      a3 = fdot2f(w[c].w, hv.w, a3);
    }
    pp[tid] = ((a0 + a1) + (a2 + a3)) + xcur + sp;
    bar_vperm();                                   // B1: pp ready

    if (tid < 128) {
      float gi = pp[uu], gf = pp[128 + uu], gg = pp[256 + uu], go = pp[384 + uu];
      c_state = sigm(gf) * c_state + sigm(gi) * tanhf_fast(gg);
      float h = sigm(go) * tanhf_fast(c_state);
      ((f16*)hfull[(n + 1) & 1])[half * 128 + uu] = (f16)h;
    }
    bar_vperm();                                   // B2: own h half in LDS

    if (n < T_SEQ - 1) {
      if (tid < 16) {
        // publish own half: 16 x uint4 stores, then release flag (lane 0)
        uint4 d = *(const uint4*)&hfull[(n + 1) & 1][half * 64 + tid * 4];
        *(uint4*)(Hx + ((size_t)(myF * 2u + (unsigned)((n + 1) & 1)) * 64) + tid * 4) = d;
        if (tid == 0)
          __hip_atomic_store(&flags[myF * 64], (unsigned)(n + 1),
                             __ATOMIC_RELEASE, __HIP_MEMORY_SCOPE_AGENT);
        // Hh history AFTER flag (not part of the protocol)
        *(uint4*)(Hh + ((size_t)(dir * T_SEQ + t) * NB + b) * HID + half * 128 + tid * 8) = d;
      } else if (tid >= 64 && tid < 80) {
        // fetch partner half
        int lt = tid - 64;
        const unsigned* pf = &flags[paF * 64];
        while (__hip_atomic_load(pf, __ATOMIC_RELAXED, __HIP_MEMORY_SCOPE_AGENT)
               < (unsigned)(n + 1)) {}
        (void)__hip_atomic_load(pf, __ATOMIC_ACQUIRE, __HIP_MEMORY_SCOPE_AGENT);
        uint4 d = *(const uint4*)(Hx + ((size_t)(paF * 2u + (unsigned)((n + 1) & 1)) * 64) + lt * 4);
        *(uint4*)&hfull[(n + 1) & 1][(half ^ 1) * 64 + lt * 4] = d;
      }
    } else {
      if (tid < 16) {
        uint4 d = *(const uint4*)&hfull[(n + 1) & 1][half * 64 + tid * 4];
        *(uint4*)(Hh + ((size_t)(dir * T_SEQ + t) * NB + b) * HID + half * 128 + tid * 8) = d;
      }
    }
    xcur = xnext;
    bar_vperm();                                   // B3: partner h in LDS
  }
}

// ---------------- E projection via MFMA 16x16x32 f16 (round-8, kept) ----------------
__launch_bounds__(256, 4)
__global__ void k_eproj(const uint32_t* __restrict__ Hdw, const uint32_t* __restrict__ WdH_dw,
                        const float* __restrict__ dbias, f16* __restrict__ E) {
  __shared__ __align__(16) uint32_t Asm[64][68];
  __shared__ __align__(16) uint32_t Wsm[64][68];
  int nt = blockIdx.x % 12;
  int t  = blockIdx.x / 12;      // 0..1022
  int n0 = nt * 64;
  int tid = threadIdx.x;
  int wave = tid >> 6, lane = tid & 63;
  int lr = lane & 15, lg = lane >> 4;

  v4f acc0 = {0,0,0,0}, acc1 = {0,0,0,0}, acc2 = {0,0,0,0}, acc3 = {0,0,0,0};

  for (int ch = 0; ch < 4; ++ch) {
    int dirc = ch >> 1, koff = (ch & 1) * 64;
    {
      int bb = tid >> 2, p = tid & 3;
      const uint32_t* asrc = Hdw + ((size_t)(dirc * T_SEQ + t) * NB + bb) * 128 + koff + p * 4;
      const uint32_t* wsrc = WdH_dw + (size_t)(n0 + bb) * 256 + ch * 64 + p * 4;
      #pragma unroll
      for (int q = 0; q < 4; ++q) {
        *(uint4*)(&Asm[bb][p * 4 + q * 16]) = *(const uint4*)(asrc + q * 16);
        *(uint4*)(&Wsm[bb][p * 4 + q * 16]) = *(const uint4*)(wsrc + q * 16);
      }
    }
    __syncthreads();
    #pragma unroll
    for (int sub = 0; sub < 4; ++sub) {            // 32 k per sub-chunk
      v8h af = __builtin_bit_cast(v8h, *(const uint4*)&Asm[wave * 16 + lr][sub * 16 + lg * 4]);
      v8h b0 = __builtin_bit_cast(v8h, *(const uint4*)&Wsm[ 0 + lr][sub * 16 + lg * 4]);
      v8h b1 = __builtin_bit_cast(v8h, *(const uint4*)&Wsm[16 + lr][sub * 16 + lg * 4]);
      v8h b2 = __builtin_bit_cast(v8h, *(const uint4*)&Wsm[32 + lr][sub * 16 + lg * 4]);
      v8h b3 = __builtin_bit_cast(v8h, *(const uint4*)&Wsm[48 + lr][sub * 16 + lg * 4]);
      acc0 = __builtin_amdgcn_mfma_f32_16x16x32_f16(af, b0, acc0, 0, 0, 0);
      acc1 = __builtin_amdgcn_mfma_f32_16x16x32_f16(af, b1, acc1, 0, 0, 0);
      acc2 = __builtin_amdgcn_mfma_f32_16x16x32_f16(af, b2, acc2, 0, 0, 0);
      acc3 = __builtin_amdgcn_mfma_f32_16x16x32_f16(af, b3, acc3, 0, 0, 0);
    }
    __syncthreads();
  }

  float db0 = dbias[n0 +  0 + lr];
  float db1 = dbias[n0 + 16 + lr];
  float db2 = dbias[n0 + 32 + lr];
  float db3 = dbias[n0 + 48 + lr];
  #pragma unroll
  for (int reg = 0; reg < 4; ++reg) {
    int m = wave * 16 + lg * 4 + reg;
    f16* Erow = E + ((size_t)t * NB + m) * DROWS + n0;
    Erow[ 0 + lr] = (f16)(acc0[reg] + db0);
    Erow[16 + lr] = (f16)(acc1[reg] + db1);
    Erow[32 + lr] = (f16)(acc2[reg] + db2);
    Erow[48 + lr] = (f16)(acc3[reg] + db3);
  }
}

// ---------------- decoder: round-8/11 proven version (512 thr, kh=tid>>8) ----------------
__launch_bounds__(512, 2)
__global__ void k_dec(const float* __restrict__ mel, const f16* __restrict__ E,
                      const uint32_t* __restrict__ WmH_dw, const uint32_t* __restrict__ WfcH_dw,
                      const float* __restrict__ bfc, float* __restrict__ out) {
  __shared__ __align__(16) uint32_t pm[40];        // prev_mel 80 f16
  __shared__ __align__(16) uint32_t h_sm[128];     // h 256 f16
  __shared__ float pp[3][256];                     // kh1 partial gate sums
  __shared__ float partial[80][4];
  __shared__ __align__(16) uint4 Ebuf[2][16 * 96]; // 2 x 24 KiB (16 steps x 768 f16)

  int b = blockIdx.x;
  int tid = threadIdx.x;
  int u = tid & 255, kh = tid >> 8;

  uint4 wm0[5], wm1[5], wm2[5];
  {
    const uint4* p0 = (const uint4*)(WmH_dw + (size_t)(u      ) * 40) + kh * 5;
    const uint4* p1 = (const uint4*)(WmH_dw + (size_t)(u + 256) * 40) + kh * 5;
    const uint4* p2 = (const uint4*)(WmH_dw + (size_t)(u + 512) * 40) + kh * 5;
    #pragma unroll
    for (int k = 0; k < 5; ++k) { wm0[k] = p0[k]; wm1[k] = p1[k]; wm2[k] = p2[k]; }
  }
  int fr = (tid < 320) ? (tid >> 2) : 0;
  int q  = tid & 3;
  uint4 wfc[8];
  {
    const uint4* wp = (const uint4*)(WfcH_dw + (size_t)fr * 128) + q * 8;
    #pragma unroll
    for (int k = 0; k < 8; ++k) wfc[k] = wp[k];
  }
  float bfcv = bfc[tid < NMEL ? tid : 0];
  if (tid < 40) {
    float m0 = mel[(size_t)b * T_SEQ * NMEL + 2 * tid];
    float m1 = mel[(size_t)b * T_SEQ * NMEL + 2 * tid + 1];
    f16x2 v; v[0] = (f16)m0; v[1] = (f16)m1;
    pm[tid] = __builtin_bit_cast(uint32_t, v);
  }

  int srow = tid >> 5, scol = tid & 31;
  {
    const uint4* src = (const uint4*)(E + ((size_t)srow * NB + b) * DROWS);
    Ebuf[0][srow * 96 + scol     ] = src[scol];
    Ebuf[0][srow * 96 + scol + 32] = src[scol + 32];
    Ebuf[0][srow * 96 + scol + 64] = src[scol + 64];
  }
  __syncthreads();

  float o_keep = 0.0f;
  for (int t = 0; t < T_SEQ - 1; ++t) {
    int w = t >> 4, s = t & 15;
    if (t > 0 && tid < NMEL)
      out[((size_t)b * (T_SEQ - 1) + (t - 1)) * NMEL + tid] = o_keep;
    uint4 st0, st1, st2;
    bool do_stage = (s == 0) && (w < 63);
    if (do_stage) {
      int rr = (w + 1) * 16 + srow; if (rr > T_SEQ - 2) rr = T_SEQ - 2;
      const uint4* src = (const uint4*)(E + ((size_t)rr * NB + b) * DROWS);
      st0 = src[scol]; st1 = src[scol + 32]; st2 = src[scol + 64];
    }

    float a0 = 0, a1 = 0, a2 = 0;
    const uint4* pm4 = ((const uint4*)pm) + kh * 5;
    #pragma unroll
    for (int k = 0; k < 5; ++k) {
      uint4 hp = pm4[k];
      a0 = fdot2f(wm0[k].x, hp.x, a0); a1 = fdot2f(wm1[k].x, hp.x, a1); a2 = fdot2f(wm2[k].x, hp.x, a2);
      a0 = fdot2f(wm0[k].y, hp.y, a0); a1 = fdot2f(wm1[k].y, hp.y, a1); a2 = fdot2f(wm2[k].y, hp.y, a2);
      a0 = fdot2f(wm0[k].z, hp.z, a0); a1 = fdot2f(wm1[k].z, hp.z, a1); a2 = fdot2f(wm2[k].z, hp.z, a2);
      a0 = fdot2f(wm0[k].w, hp.w, a0); a1 = fdot2f(wm1[k].w, hp.w, a1); a2 = fdot2f(wm2[k].w, hp.w, a2);
    }
    if (kh == 1) { pp[0][u] = a0; pp[1][u] = a1; pp[2][u] = a2; }
    __syncthreads();                               // B1: pp ready

    if (kh == 0) {
      const f16* Erow = (const f16*)&Ebuf[w & 1][s * 96];
      float gi = a0 + pp[0][u] + (float)Erow[u];
      float gg = a1 + pp[1][u] + (float)Erow[u + 256];
      float go = a2 + pp[2][u] + (float)Erow[u + 512];
      float cc = sigm(gi) * tanhf_fast(gg);
      float h  = sigm(go) * tanhf_fast(cc);
      ((f16*)h_sm)[u] = (f16)h;
    }
    if (do_stage) {
      Ebuf[(w + 1) & 1][srow * 96 + scol     ] = st0;
      Ebuf[(w + 1) & 1][srow * 96 + scol + 32] = st1;
      Ebuf[(w + 1) & 1][srow * 96 + scol + 64] = st2;
    }
    __syncthreads();                               // B2: h ready

    if (tid < 320) {
      const uint4* hrow = ((const uint4*)h_sm) + q * 8;
      float s0 = 0, s1 = 0, s2 = 0, s3 = 0;
      #pragma unroll
      for (int kk = 0; kk < 8; ++kk) {
        uint4 hq = hrow[kk];
        s0 = fdot2f(wfc[kk].x, hq.x, s0); s1 = fdot2f(wfc[kk].y, hq.y, s1);
        s2 = fdot2f(wfc[kk].z, hq.z, s2); s3 = fdot2f(wfc[kk].w, hq.w, s3);
      }
      partial[fr][q] = (s0 + s1) + (s2 + s3);
    }
    __syncthreads();                               // B3: partial ready

    if (tid < NMEL) {
      float o = ((partial[tid][0] + partial[tid][1]) +
                 (partial[tid][2] + partial[tid][3])) + bfcv;
      o_keep = o;
      ((f16*)pm)[tid] = (f16)o;
    }
    __syncthreads();                               // B4: pm ready
  }
  if (tid < NMEL)
    out[((size_t)b * (T_SEQ - 1) + (T_SEQ - 2)) * NMEL + tid] = o_keep;
}

// ---------------- host ----------------
extern "C" void kernel_launch(void* const* d_in, const int* in_sizes, int n_in,
                              void* d_out, int out_size, void* d_ws, size_t ws_size,
                              hipStream_t stream) {
  const int*   text_seq   = (const int*)d_in[0];
  const float* mel        = (const float*)d_in[1];
  const int*   speaker_id = (const int*)d_in[2];
  const float* emb_text   = (const float*)d_in[3];
  const float* emb_spk    = (const float*)d_in[4];
  const float* Wih_f = (const float*)d_in[5];
  const float* Whh_f = (const float*)d_in[6];
  const float* bih_f = (const float*)d_in[7];
  const float* bhh_f = (const float*)d_in[8];
  const float* Wih_b = (const float*)d_in[9];
  const float* Whh_b = (const float*)d_in[10];
  const float* bih_b = (const float*)d_in[11];
  const float* bhh_b = (const float*)d_in[12];
  const float* Wih_d = (const float*)d_in[13];
  const float* bih_d = (const float*)d_in[14];
  const float* bhh_d = (const float*)d_in[15];
  const float* Wfc   = (const float*)d_in[16];
  const float* bfc   = (const float*)d_in[17];
  float* out = (float*)d_out;

  char* base = (char*)d_ws;
  size_t off = 0;
  auto take = [&](size_t n) -> char* {
    off = (off + 255) & ~(size_t)255;
    char* r = base + off;
    off += n;
    return r;
  };
  float*        TP    = (float*)take((size_t)2 * VOCAB * GROWS * 4);
  float*        SP    = (float*)take((size_t)2 * NSPK * GROWS * 4);
  f16*          WhhH  = (f16*)take((size_t)2 * GROWS * HID * 2);
  f16*          WmH   = (f16*)take((size_t)DROWS * 80 * 2);
  f16*          WdH   = (f16*)take((size_t)DROWS * 512 * 2);
  f16*          WfcH  = (f16*)take((size_t)NMEL * HID * 2);
  float*        dbias = (float*)take((size_t)DROWS * 4);
  unsigned int* flags = (unsigned int*)take((size_t)256 * 64 * 4);   // 64KB padded flags
  uint32_t*     Hx    = (uint32_t*)take((size_t)256 * 2 * 64 * 4);   // 128KB exchange slots
  f16*          Hh    = (f16*)take((size_t)2 * T_SEQ * NB * HID * 2);
  f16*          E     = (f16*)take((size_t)(T_SEQ - 1) * NB * DROWS * 2);
  if (off > ws_size) return;   // insufficient workspace -> fail visibly

  k_tp  <<<2 * VOCAB, 256, 0, stream>>>(Wih_f, Wih_b, emb_text, TP);
  k_sp  <<<2 * NSPK, 256, 0, stream>>>(Wih_f, Wih_b, bih_f, bhh_f, bih_b, bhh_b, emb_spk, SP);
  k_whh <<<2048, 256, 0, stream>>>(Whh_f, Whh_b, WhhH);
  k_decw<<<DROWS, 256, 0, stream>>>(Wih_d, bih_d, bhh_d, WmH, WdH, dbias);
  k_misc<<<80, 256, 0, stream>>>(Wfc, WfcH, flags);
  k_enc <<<256, 512, 0, stream>>>(text_seq, speaker_id, TP, SP,
                                  (const uint32_t*)WhhH, Hh, Hx, flags);
  k_eproj<<<(T_SEQ - 1) * 12, 256, 0, stream>>>((const uint32_t*)Hh,
                                                (const uint32_t*)WdH, dbias, E);
  k_dec <<<NB, 512, 0, stream>>>(mel, E, (const uint32_t*)WmH,
                                 (const uint32_t*)WfcH, bfc, out);
}

// Round 16
// 2828.125 us; speedup vs baseline: 2.1706x; 2.1706x over previous
//
#include <hip/hip_runtime.h>
#include <hip/hip_fp16.h>
#include <stdint.h>

#define T_SEQ 1024
#define NB    64
#define VOCAB 34
#define NSPK  128
#define DTXT  512
#define HID   256
#define NMEL  80
#define GROWS 1024   // 4*HID gate rows
#define DROWS 768    // decoder rows actually used: i,g,o

typedef _Float16 f16;
typedef _Float16 f16x2 __attribute__((ext_vector_type(2)));
typedef _Float16 v8h __attribute__((ext_vector_type(8)));
typedef float v4f __attribute__((ext_vector_type(4)));

__device__ __forceinline__ float fdot2f(uint32_t a, uint32_t b, float c) {
  return __builtin_amdgcn_fdot2(__builtin_bit_cast(f16x2, a),
                                __builtin_bit_cast(f16x2, b), c, false);
}
__device__ __forceinline__ float sigm(float x) { return 1.0f / (1.0f + __expf(-x)); }
__device__ __forceinline__ float tanhf_fast(float x) {
  float e = __expf(2.0f * x);
  return 1.0f - 2.0f / (e + 1.0f);
}
// Barrier that drains LDS ops but lets global loads/stores stay in flight.
__device__ __forceinline__ void bar_vperm() {
  asm volatile("s_waitcnt lgkmcnt(0)\n\ts_barrier" ::: "memory");
  __builtin_amdgcn_sched_barrier(0);
}

// ---------------- prep kernels ----------------

__global__ void k_tp(const float* __restrict__ Wf, const float* __restrict__ Wb,
                     const float* __restrict__ emb_text, float* __restrict__ TP) {
  int blk = blockIdx.x; int dir = blk / VOCAB; int v = blk - dir * VOCAB;
  const float* W = dir ? Wb : Wf;
  const float4* e4 = (const float4*)(emb_text + (size_t)v * DTXT);
  for (int r = threadIdx.x; r < GROWS; r += 256) {
    const float4* w4 = (const float4*)(W + (size_t)r * 576);
    float a0 = 0, a1 = 0, a2 = 0, a3 = 0;
    #pragma unroll 4
    for (int d = 0; d < DTXT / 4; ++d) {
      float4 ev = e4[d], wv = w4[d];
      a0 += ev.x * wv.x; a1 += ev.y * wv.y;
      a2 += ev.z * wv.z; a3 += ev.w * wv.w;
    }
    TP[(size_t)(dir * VOCAB + v) * GROWS + r] = (a0 + a1) + (a2 + a3);
  }
}

__global__ void k_sp(const float* __restrict__ Wf, const float* __restrict__ Wb,
                     const float* __restrict__ bihf, const float* __restrict__ bhhf,
                     const float* __restrict__ bihb, const float* __restrict__ bhhb,
                     const float* __restrict__ emb_spk, float* __restrict__ SP) {
  int blk = blockIdx.x; int dir = blk >> 7; int s = blk & 127;
  const float* W  = dir ? Wb : Wf;
  const float* bi = dir ? bihb : bihf;
  const float* bh = dir ? bhhb : bhhf;
  const float4* e4 = (const float4*)(emb_spk + (size_t)s * 64);
  for (int r = threadIdx.x; r < GROWS; r += 256) {
    const float4* w4 = (const float4*)(W + (size_t)r * 576 + 512);
    float a0 = 0, a1 = 0, a2 = 0, a3 = 0;
    #pragma unroll
    for (int d = 0; d < 16; ++d) {
      float4 ev = e4[d], wv = w4[d];
      a0 += ev.x * wv.x; a1 += ev.y * wv.y;
      a2 += ev.z * wv.z; a3 += ev.w * wv.w;
    }
    SP[(size_t)(dir * NSPK + s) * GROWS + r] = bi[r] + bh[r] + (a0 + a1) + (a2 + a3);
  }
}

__global__ void k_whh(const float* __restrict__ Whhf, const float* __restrict__ Whhb,
                      f16* __restrict__ WhhH) {
  int idx = blockIdx.x * 256 + threadIdx.x;
  if (idx < 2 * GROWS * HID) {
    int dir = idx >> 18; int rem = idx & (GROWS * HID - 1);
    WhhH[idx] = (f16)(dir ? Whhb[rem] : Whhf[rem]);
  }
}

// decoder weights, row-reordered to [i(256), g(256), o(256)] (f gate unused)
__global__ void k_decw(const float* __restrict__ Wih_d, const float* __restrict__ bih_d,
                       const float* __restrict__ bhh_d,
                       f16* __restrict__ WmH, f16* __restrict__ WdH, float* __restrict__ dbias) {
  int r = blockIdx.x;                 // 0..767 in [i,g,o] space
  int src = (r < 256) ? r : (r + 256);
  const float* w = Wih_d + (size_t)src * 592;
  for (int k = threadIdx.x; k < 592; k += 256) {
    float v = w[k];
    if (k < 80) WmH[(size_t)r * 80 + k] = (f16)v;
    else        WdH[(size_t)r * 512 + (k - 80)] = (f16)v;
  }
  if (threadIdx.x == 0) dbias[r] = bih_d[src] + bhh_d[src];
}

__global__ void k_misc(const float* __restrict__ Wfc, f16* __restrict__ WfcH) {
  int idx = blockIdx.x * 256 + threadIdx.x;
  if (idx < NMEL * HID) WfcH[idx] = (f16)Wfc[idx];
}

// ---------------- encoder: round-11 proven version (1743us) ----------------
__launch_bounds__(512, 2)
__global__ void k_enc(const int* __restrict__ text_seq, const int* __restrict__ speaker_id,
                      const float* __restrict__ TP, const float* __restrict__ SP,
                      const uint32_t* __restrict__ WhhH_dw,
                      f16* __restrict__ Hh) {           // [2][1024][64][256] f16
  __shared__ __align__(16) uint4 wtail[16 * 512];       // 128 KiB: [(g*4+j)][tid]
  __shared__ __align__(16) uint32_t hbuf[2][128];       // double-buffered h (256 f16)
  __shared__ float pp[4][256];                          // kh1 partial gate sums
  __shared__ int tseq[T_SEQ];

  int wg = blockIdx.x;          // 0..127 = dir*64 + b
  int dir = wg >> 6, b = wg & 63;
  int tid = threadIdx.x;
  int u = tid & 255, kh = tid >> 8;

  uint4 w0[12], w1[12], w2[12], w3[12];
  {
    const uint4* p0 = (const uint4*)(WhhH_dw + ((size_t)(dir << 10) + u      ) * 128 + (kh << 6));
    const uint4* p1 = (const uint4*)(WhhH_dw + ((size_t)(dir << 10) + u + 256) * 128 + (kh << 6));
    const uint4* p2 = (const uint4*)(WhhH_dw + ((size_t)(dir << 10) + u + 512) * 128 + (kh << 6));
    const uint4* p3 = (const uint4*)(WhhH_dw + ((size_t)(dir << 10) + u + 768) * 128 + (kh << 6));
    #pragma unroll
    for (int i = 0; i < 12; ++i) { w0[i] = p0[i]; w1[i] = p1[i]; w2[i] = p2[i]; w3[i] = p3[i]; }
    #pragma unroll
    for (int j = 0; j < 4; ++j) {
      wtail[(0 * 4 + j) * 512 + tid] = p0[12 + j];
      wtail[(1 * 4 + j) * 512 + tid] = p1[12 + j];
      wtail[(2 * 4 + j) * 512 + tid] = p2[12 + j];
      wtail[(3 * 4 + j) * 512 + tid] = p3[12 + j];
    }
  }
  for (int i = tid; i < T_SEQ; i += 512) tseq[i] = text_seq[b * T_SEQ + i];
  if (tid < 128) hbuf[0][tid] = 0u;
  float sp0 = 0, sp1 = 0, sp2 = 0, sp3 = 0;
  if (kh == 0) {
    int spk = speaker_id[b];
    sp0 = SP[(size_t)(dir * NSPK + spk) * GROWS + u];
    sp1 = SP[(size_t)(dir * NSPK + spk) * GROWS + u + 256];
    sp2 = SP[(size_t)(dir * NSPK + spk) * GROWS + u + 512];
    sp3 = SP[(size_t)(dir * NSPK + spk) * GROWS + u + 768];
  }
  const float* TPd = TP + (size_t)dir * VOCAB * GROWS;
  float c_state = 0.0f;
  __syncthreads();

  float x0 = 0, x1 = 0, x2 = 0, x3 = 0;
  if (kh == 0) {
    int v = tseq[dir ? (T_SEQ - 1) : 0];
    x0 = TPd[(size_t)v * GROWS + u];
    x1 = TPd[(size_t)v * GROWS + u + 256];
    x2 = TPd[(size_t)v * GROWS + u + 512];
    x3 = TPd[(size_t)v * GROWS + u + 768];
  }

  float h_keep = 0.0f; int t_keep = 0;
  for (int n = 0; n < T_SEQ; ++n) {
    int t = dir ? (T_SEQ - 1 - n) : n;
    float xn0 = 0, xn1 = 0, xn2 = 0, xn3 = 0;
    if (kh == 0) {
      if (n > 0)
        Hh[((size_t)(dir * T_SEQ + t_keep) * NB + b) * HID + u] = (f16)h_keep;
      int tn = dir ? (T_SEQ - 2 - n) : (n + 1);
      tn = tn < 0 ? 0 : (tn > T_SEQ - 1 ? T_SEQ - 1 : tn);
      int vn = tseq[tn];
      xn0 = TPd[(size_t)vn * GROWS + u];
      xn1 = TPd[(size_t)vn * GROWS + u + 256];
      xn2 = TPd[(size_t)vn * GROWS + u + 512];
      xn3 = TPd[(size_t)vn * GROWS + u + 768];
    }

    float i0 = 0, i1 = 0, f0 = 0, f1 = 0, g0 = 0, g1 = 0, o0 = 0, o1 = 0;
    const uint4* h4 = ((const uint4*)hbuf[n & 1]) + (kh << 4);
    #pragma unroll
    for (int c = 0; c < 12; ++c) {
      uint4 hv = h4[c];
      i0 = fdot2f(w0[c].x, hv.x, i0); f0 = fdot2f(w1[c].x, hv.x, f0);
      g0 = fdot2f(w2[c].x, hv.x, g0); o0 = fdot2f(w3[c].x, hv.x, o0);
      i1 = fdot2f(w0[c].y, hv.y, i1); f1 = fdot2f(w1[c].y, hv.y, f1);
      g1 = fdot2f(w2[c].y, hv.y, g1); o1 = fdot2f(w3[c].y, hv.y, o1);
      i0 = fdot2f(w0[c].z, hv.z, i0); f0 = fdot2f(w1[c].z, hv.z, f0);
      g0 = fdot2f(w2[c].z, hv.z, g0); o0 = fdot2f(w3[c].z, hv.z, o0);
      i1 = fdot2f(w0[c].w, hv.w, i1); f1 = fdot2f(w1[c].w, hv.w, f1);
      g1 = fdot2f(w2[c].w, hv.w, g1); o1 = fdot2f(w3[c].w, hv.w, o1);
    }
    #pragma unroll
    for (int j = 0; j < 4; ++j) {
      uint4 hv = h4[12 + j];
      uint4 t0v = wtail[(0 * 4 + j) * 512 + tid];
      uint4 t1v = wtail[(1 * 4 + j) * 512 + tid];
      uint4 t2v = wtail[(2 * 4 + j) * 512 + tid];
      uint4 t3v = wtail[(3 * 4 + j) * 512 + tid];
      i0 = fdot2f(t0v.x, hv.x, i0); f0 = fdot2f(t1v.x, hv.x, f0);
      g0 = fdot2f(t2v.x, hv.x, g0); o0 = fdot2f(t3v.x, hv.x, o0);
      i1 = fdot2f(t0v.y, hv.y, i1); f1 = fdot2f(t1v.y, hv.y, f1);
      g1 = fdot2f(t2v.y, hv.y, g1); o1 = fdot2f(t3v.y, hv.y, o1);
      i0 = fdot2f(t0v.z, hv.z, i0); f0 = fdot2f(t1v.z, hv.z, f0);
      g0 = fdot2f(t2v.z, hv.z, g0); o0 = fdot2f(t3v.z, hv.z, o0);
      i1 = fdot2f(t0v.w, hv.w, i1); f1 = fdot2f(t1v.w, hv.w, f1);
      g1 = fdot2f(t2v.w, hv.w, g1); o1 = fdot2f(t3v.w, hv.w, o1);
    }
    if (kh == 1) {
      pp[0][u] = i0 + i1;
      pp[1][u] = f0 + f1;
      pp[2][u] = g0 + g1;
      pp[3][u] = o0 + o1;
    }
    bar_vperm();                                   // B1: pp ready (vmem stays in flight)

    if (kh == 0) {
      float gi = (i0 + i1) + pp[0][u] + x0 + sp0;
      float gf = (f0 + f1) + pp[1][u] + x1 + sp1;
      float gg = (g0 + g1) + pp[2][u] + x2 + sp2;
      float go = (o0 + o1) + pp[3][u] + x3 + sp3;
      c_state = sigm(gf) * c_state + sigm(gi) * tanhf_fast(gg);
      float h = sigm(go) * tanhf_fast(c_state);
      ((f16*)hbuf[(n + 1) & 1])[u] = (f16)h;
      h_keep = h; t_keep = t;
      x0 = xn0; x1 = xn1; x2 = xn2; x3 = xn3;
    }
    bar_vperm();                                   // B2: h ready
  }
  if (kh == 0)
    Hh[((size_t)(dir * T_SEQ + t_keep) * NB + b) * HID + u] = (f16)h_keep;
}

// ---------------- E projection via MFMA 16x16x32 f16 (round-8, kept) ----------------
__launch_bounds__(256, 4)
__global__ void k_eproj(const uint32_t* __restrict__ Hdw, const uint32_t* __restrict__ WdH_dw,
                        const float* __restrict__ dbias, f16* __restrict__ E) {
  __shared__ __align__(16) uint32_t Asm[64][68];
  __shared__ __align__(16) uint32_t Wsm[64][68];
  int nt = blockIdx.x % 12;
  int t  = blockIdx.x / 12;      // 0..1022
  int n0 = nt * 64;
  int tid = threadIdx.x;
  int wave = tid >> 6, lane = tid & 63;
  int lr = lane & 15, lg = lane >> 4;

  v4f acc0 = {0,0,0,0}, acc1 = {0,0,0,0}, acc2 = {0,0,0,0}, acc3 = {0,0,0,0};

  for (int ch = 0; ch < 4; ++ch) {
    int dirc = ch >> 1, koff = (ch & 1) * 64;
    {
      int bb = tid >> 2, p = tid & 3;
      const uint32_t* asrc = Hdw + ((size_t)(dirc * T_SEQ + t) * NB + bb) * 128 + koff + p * 4;
      const uint32_t* wsrc = WdH_dw + (size_t)(n0 + bb) * 256 + ch * 64 + p * 4;
      #pragma unroll
      for (int q = 0; q < 4; ++q) {
        *(uint4*)(&Asm[bb][p * 4 + q * 16]) = *(const uint4*)(asrc + q * 16);
        *(uint4*)(&Wsm[bb][p * 4 + q * 16]) = *(const uint4*)(wsrc + q * 16);
      }
    }
    __syncthreads();
    #pragma unroll
    for (int sub = 0; sub < 4; ++sub) {            // 32 k per sub-chunk
      v8h af = __builtin_bit_cast(v8h, *(const uint4*)&Asm[wave * 16 + lr][sub * 16 + lg * 4]);
      v8h b0 = __builtin_bit_cast(v8h, *(const uint4*)&Wsm[ 0 + lr][sub * 16 + lg * 4]);
      v8h b1 = __builtin_bit_cast(v8h, *(const uint4*)&Wsm[16 + lr][sub * 16 + lg * 4]);
      v8h b2 = __builtin_bit_cast(v8h, *(const uint4*)&Wsm[32 + lr][sub * 16 + lg * 4]);
      v8h b3 = __builtin_bit_cast(v8h, *(const uint4*)&Wsm[48 + lr][sub * 16 + lg * 4]);
      acc0 = __builtin_amdgcn_mfma_f32_16x16x32_f16(af, b0, acc0, 0, 0, 0);
      acc1 = __builtin_amdgcn_mfma_f32_16x16x32_f16(af, b1, acc1, 0, 0, 0);
      acc2 = __builtin_amdgcn_mfma_f32_16x16x32_f16(af, b2, acc2, 0, 0, 0);
      acc3 = __builtin_amdgcn_mfma_f32_16x16x32_f16(af, b3, acc3, 0, 0, 0);
    }
    __syncthreads();
  }

  float db0 = dbias[n0 +  0 + lr];
  float db1 = dbias[n0 + 16 + lr];
  float db2 = dbias[n0 + 32 + lr];
  float db3 = dbias[n0 + 48 + lr];
  #pragma unroll
  for (int reg = 0; reg < 4; ++reg) {
    int m = wave * 16 + lg * 4 + reg;
    f16* Erow = E + ((size_t)t * NB + m) * DROWS + n0;
    Erow[ 0 + lr] = (f16)(acc0[reg] + db0);
    Erow[16 + lr] = (f16)(acc1[reg] + db1);
    Erow[32 + lr] = (f16)(acc2[reg] + db2);
    Erow[48 + lr] = (f16)(acc3[reg] + db3);
  }
}

// ---------------- decoder: round-8/11 proven version (512 thr, kh=tid>>8) ----------------
__launch_bounds__(512, 2)
__global__ void k_dec(const float* __restrict__ mel, const f16* __restrict__ E,
                      const uint32_t* __restrict__ WmH_dw, const uint32_t* __restrict__ WfcH_dw,
                      const float* __restrict__ bfc, float* __restrict__ out) {
  __shared__ __align__(16) uint32_t pm[40];        // prev_mel 80 f16
  __shared__ __align__(16) uint32_t h_sm[128];     // h 256 f16
  __shared__ float pp[3][256];                     // kh1 partial gate sums
  __shared__ float partial[80][4];
  __shared__ __align__(16) uint4 Ebuf[2][16 * 96]; // 2 x 24 KiB (16 steps x 768 f16)

  int b = blockIdx.x;
  int tid = threadIdx.x;
  int u = tid & 255, kh = tid >> 8;

  uint4 wm0[5], wm1[5], wm2[5];
  {
    const uint4* p0 = (const uint4*)(WmH_dw + (size_t)(u      ) * 40) + kh * 5;
    const uint4* p1 = (const uint4*)(WmH_dw + (size_t)(u + 256) * 40) + kh * 5;
    const uint4* p2 = (const uint4*)(WmH_dw + (size_t)(u + 512) * 40) + kh * 5;
    #pragma unroll
    for (int k = 0; k < 5; ++k) { wm0[k] = p0[k]; wm1[k] = p1[k]; wm2[k] = p2[k]; }
  }
  int fr = (tid < 320) ? (tid >> 2) : 0;
  int q  = tid & 3;
  uint4 wfc[8];
  {
    const uint4* wp = (const uint4*)(WfcH_dw + (size_t)fr * 128) + q * 8;
    #pragma unroll
    for (int k = 0; k < 8; ++k) wfc[k] = wp[k];
  }
  float bfcv = bfc[tid < NMEL ? tid : 0];
  if (tid < 40) {
    float m0 = mel[(size_t)b * T_SEQ * NMEL + 2 * tid];
    float m1 = mel[(size_t)b * T_SEQ * NMEL + 2 * tid + 1];
    f16x2 v; v[0] = (f16)m0; v[1] = (f16)m1;
    pm[tid] = __builtin_bit_cast(uint32_t, v);
  }

  int srow = tid >> 5, scol = tid & 31;
  {
    const uint4* src = (const uint4*)(E + ((size_t)srow * NB + b) * DROWS);
    Ebuf[0][srow * 96 + scol     ] = src[scol];
    Ebuf[0][srow * 96 + scol + 32] = src[scol + 32];
    Ebuf[0][srow * 96 + scol + 64] = src[scol + 64];
  }
  __syncthreads();

  float o_keep = 0.0f;
  for (int t = 0; t < T_SEQ - 1; ++t) {
    int w = t >> 4, s = t & 15;
    if (t > 0 && tid < NMEL)
      out[((size_t)b * (T_SEQ - 1) + (t - 1)) * NMEL + tid] = o_keep;
    uint4 st0, st1, st2;
    bool do_stage = (s == 0) && (w < 63);
    if (do_stage) {
      int rr = (w + 1) * 16 + srow; if (rr > T_SEQ - 2) rr = T_SEQ - 2;
      const uint4* src = (const uint4*)(E + ((size_t)rr * NB + b) * DROWS);
      st0 = src[scol]; st1 = src[scol + 32]; st2 = src[scol + 64];
    }

    float a0 = 0, a1 = 0, a2 = 0;
    const uint4* pm4 = ((const uint4*)pm) + kh * 5;
    #pragma unroll
    for (int k = 0; k < 5; ++k) {
      uint4 hp = pm4[k];
      a0 = fdot2f(wm0[k].x, hp.x, a0); a1 = fdot2f(wm1[k].x, hp.x, a1); a2 = fdot2f(wm2[k].x, hp.x, a2);
      a0 = fdot2f(wm0[k].y, hp.y, a0); a1 = fdot2f(wm1[k].y, hp.y, a1); a2 = fdot2f(wm2[k].y, hp.y, a2);
      a0 = fdot2f(wm0[k].z, hp.z, a0); a1 = fdot2f(wm1[k].z, hp.z, a1); a2 = fdot2f(wm2[k].z, hp.z, a2);
      a0 = fdot2f(wm0[k].w, hp.w, a0); a1 = fdot2f(wm1[k].w, hp.w, a1); a2 = fdot2f(wm2[k].w, hp.w, a2);
    }
    if (kh == 1) { pp[0][u] = a0; pp[1][u] = a1; pp[2][u] = a2; }
    __syncthreads();                               // B1: pp ready

    if (kh == 0) {
      const f16* Erow = (const f16*)&Ebuf[w & 1][s * 96];
      float gi = a0 + pp[0][u] + (float)Erow[u];
      float gg = a1 + pp[1][u] + (float)Erow[u + 256];
      float go = a2 + pp[2][u] + (float)Erow[u + 512];
      float cc = sigm(gi) * tanhf_fast(gg);
      float h  = sigm(go) * tanhf_fast(cc);
      ((f16*)h_sm)[u] = (f16)h;
    }
    if (do_stage) {
      Ebuf[(w + 1) & 1][srow * 96 + scol     ] = st0;
      Ebuf[(w + 1) & 1][srow * 96 + scol + 32] = st1;
      Ebuf[(w + 1) & 1][srow * 96 + scol + 64] = st2;
    }
    __syncthreads();                               // B2: h ready

    if (tid < 320) {
      const uint4* hrow = ((const uint4*)h_sm) + q * 8;
      float s0 = 0, s1 = 0, s2 = 0, s3 = 0;
      #pragma unroll
      for (int kk = 0; kk < 8; ++kk) {
        uint4 hq = hrow[kk];
        s0 = fdot2f(wfc[kk].x, hq.x, s0); s1 = fdot2f(wfc[kk].y, hq.y, s1);
        s2 = fdot2f(wfc[kk].z, hq.z, s2); s3 = fdot2f(wfc[kk].w, hq.w, s3);
      }
      partial[fr][q] = (s0 + s1) + (s2 + s3);
    }
    __syncthreads();                               // B3: partial ready

    if (tid < NMEL) {
      float o = ((partial[tid][0] + partial[tid][1]) +
                 (partial[tid][2] + partial[tid][3])) + bfcv;
      o_keep = o;
      ((f16*)pm)[tid] = (f16)o;
    }
    __syncthreads();                               // B4: pm ready
  }
  if (tid < NMEL)
    out[((size_t)b * (T_SEQ - 1) + (T_SEQ - 2)) * NMEL + tid] = o_keep;
}

// ---------------- host ----------------
extern "C" void kernel_launch(void* const* d_in, const int* in_sizes, int n_in,
                              void* d_out, int out_size, void* d_ws, size_t ws_size,
                              hipStream_t stream) {
  const int*   text_seq   = (const int*)d_in[0];
  const float* mel        = (const float*)d_in[1];
  const int*   speaker_id = (const int*)d_in[2];
  const float* emb_text   = (const float*)d_in[3];
  const float* emb_spk    = (const float*)d_in[4];
  const float* Wih_f = (const float*)d_in[5];
  const float* Whh_f = (const float*)d_in[6];
  const float* bih_f = (const float*)d_in[7];
  const float* bhh_f = (const float*)d_in[8];
  const float* Wih_b = (const float*)d_in[9];
  const float* Whh_b = (const float*)d_in[10];
  const float* bih_b = (const float*)d_in[11];
  const float* bhh_b = (const float*)d_in[12];
  const float* Wih_d = (const float*)d_in[13];
  const float* bih_d = (const float*)d_in[14];
  const float* bhh_d = (const float*)d_in[15];
  const float* Wfc   = (const float*)d_in[16];
  const float* bfc   = (const float*)d_in[17];
  float* out = (float*)d_out;

  char* base = (char*)d_ws;
  size_t off = 0;
  auto take = [&](size_t n) -> char* {
    off = (off + 255) & ~(size_t)255;
    char* r = base + off;
    off += n;
    return r;
  };
  float*        TP    = (float*)take((size_t)2 * VOCAB * GROWS * 4);
  float*        SP    = (float*)take((size_t)2 * NSPK * GROWS * 4);
  f16*          WhhH  = (f16*)take((size_t)2 * GROWS * HID * 2);
  f16*          WmH   = (f16*)take((size_t)DROWS * 80 * 2);
  f16*          WdH   = (f16*)take((size_t)DROWS * 512 * 2);
  f16*          WfcH  = (f16*)take((size_t)NMEL * HID * 2);
  float*        dbias = (float*)take((size_t)DROWS * 4);
  f16*          Hh    = (f16*)take((size_t)2 * T_SEQ * NB * HID * 2);
  f16*          E     = (f16*)take((size_t)(T_SEQ - 1) * NB * DROWS * 2);
  if (off > ws_size) return;   // insufficient workspace -> fail visibly

  k_tp  <<<2 * VOCAB, 256, 0, stream>>>(Wih_f, Wih_b, emb_text, TP);
  k_sp  <<<2 * NSPK, 256, 0, stream>>>(Wih_f, Wih_b, bih_f, bhh_f, bih_b, bhh_b, emb_spk, SP);
  k_whh <<<2048, 256, 0, stream>>>(Whh_f, Whh_b, WhhH);
  k_decw<<<DROWS, 256, 0, stream>>>(Wih_d, bih_d, bhh_d, WmH, WdH, dbias);
  k_misc<<<80, 256, 0, stream>>>(Wfc, WfcH);
  k_enc <<<128, 512, 0, stream>>>(text_seq, speaker_id, TP, SP,
                                  (const uint32_t*)WhhH, Hh);
  k_eproj<<<(T_SEQ - 1) * 12, 256, 0, stream>>>((const uint32_t*)Hh,
                                                (const uint32_t*)WdH, dbias, E);
  k_dec <<<NB, 512, 0, stream>>>(mel, E, (const uint32_t*)WmH,
                                 (const uint32_t*)WfcH, bfc, out);
}